// Round 1
// baseline (1898.984 us; speedup 1.0000x reference)
//
#include <hip/hip_runtime.h>
#include <math.h>

// Sizes
// B=8, IN=2, N=512, T_IN=13, RC=DC=32, SC=256, EC=512, EMB=16, DATT=16, L=8

__global__ void k_init_norm(float* normP){
    int t = threadIdx.x; // 64 threads
    normP[t] = (t < 32) ? 1.0f : 0.0f;
}

// qe/ke[l][n][16] = bias + W[:,32:48] @ gat[:,n]
__global__ void k_emb(const float* __restrict__ qw, const float* __restrict__ qb,
                      const float* __restrict__ kw, const float* __restrict__ kb,
                      const float* __restrict__ gat, float* __restrict__ qe, float* __restrict__ ke){
    int idx = blockIdx.x*256 + threadIdx.x;
    const int total = 8*512*16;
    if (idx >= 2*total) return;
    bool isK = idx >= total;
    int id = isK ? idx - total : idx;
    int dq = id & 15; int n = (id >> 4) & 511; int l = id >> 13;
    const float* w = isK ? kw : qw;
    const float* bi = isK ? kb : qb;
    float acc = bi[l*16 + dq];
    const float* wrow = w + (l*16 + dq)*48 + 32;
    #pragma unroll
    for (int e = 0; e < 16; e++) acc += wrow[e] * gat[e*512 + n];
    (isK ? ke : qe)[(l*512 + n)*16 + dq] = acc;
}

// x0[b][t][c][n] = start pw
__global__ void k_start(const float* __restrict__ inp, const float* __restrict__ sw,
                        const float* __restrict__ sb, float* __restrict__ x0){
    int idx = blockIdx.x*256 + threadIdx.x;
    if (idx >= 8*13*32*512) return;
    int n = idx & 511; int c = (idx >> 9) & 31; int r = idx >> 14;
    int t = r % 13; int b = r / 13;
    float v0 = inp[((b*2 + 0)*512 + n)*13 + t];
    float v1 = inp[((b*2 + 1)*512 + n)*13 + t];
    x0[idx] = sb[c] + sw[c*2 + 0]*v0 + sw[c*2 + 1]*v1;
}

// gated dilated conv + q/k projections. xin layout [b][Tin][c][n] (pre-BN raw; normP applied on read)
__global__ __launch_bounds__(128) void k_gated(
    const float* __restrict__ xin, int Tin, int d, int Tout,
    const float* __restrict__ normP,
    const float* __restrict__ fw, const float* __restrict__ fb,
    const float* __restrict__ gw, const float* __restrict__ gb,
    const float* __restrict__ qw, const float* __restrict__ kw,   // [16][48] rows (use cols 0..31)
    const float* __restrict__ qe, const float* __restrict__ ke,   // [512][16]
    float* __restrict__ xc, float* __restrict__ qo, float* __restrict__ ko)
{
    __shared__ float xs[2][32][128];
    __shared__ float fws[2048];
    __shared__ float gws[2048];
    __shared__ float qws[512];
    __shared__ float kws[512];
    int tid = threadIdx.x;
    int nb = blockIdx.x, t = blockIdx.y, b = blockIdx.z;
    int n0 = nb*128;
    for (int e = tid; e < 2048; e += 128){ fws[e] = fw[e]; gws[e] = gw[e]; }
    for (int e = tid; e < 512; e += 128){
        qws[e] = qw[(e >> 5)*48 + (e & 31)];
        kws[e] = kw[(e >> 5)*48 + (e & 31)];
    }
    const float* A = normP; const float* Bc = normP + 32;
    for (int e = tid; e < 2*32*128; e += 128){
        int kwi = e >> 12; int c = (e >> 7) & 31; int nn = e & 127;
        float v = xin[((size_t)(b*Tin + t + kwi*d)*32 + c)*512 + n0 + nn];
        xs[kwi][c][nn] = A[c]*v + Bc[c];
    }
    __syncthreads();
    int n = n0 + tid;
    float xr[32];
    #pragma unroll
    for (int c = 0; c < 32; c++){
        float fa = fb[c], ga = gb[c];
        #pragma unroll
        for (int r = 0; r < 32; r++){
            float x0v = xs[0][r][tid], x1v = xs[1][r][tid];
            fa += fws[(c*32+r)*2]*x0v + fws[(c*32+r)*2+1]*x1v;
            ga += gws[(c*32+r)*2]*x0v + gws[(c*32+r)*2+1]*x1v;
        }
        float v = tanhf(fa) * (1.0f/(1.0f + __expf(-ga)));
        xr[c] = v;
        xc[((size_t)(b*Tout + t)*32 + c)*512 + n] = v;
    }
    float qv[16], kv[16];
    #pragma unroll
    for (int j = 0; j < 16; j++){ qv[j] = qe[n*16 + j]; kv[j] = ke[n*16 + j]; }
    #pragma unroll
    for (int j = 0; j < 16; j++){
        float a = qv[j], bb2 = kv[j];
        #pragma unroll
        for (int c = 0; c < 32; c++){ a += qws[j*32 + c]*xr[c]; bb2 += kws[j*32 + c]*xr[c]; }
        qv[j] = a; kv[j] = bb2;
    }
    float* qrow = qo + ((size_t)(b*Tout + t)*512 + n)*16;
    float* krow = ko + ((size_t)(b*Tout + t)*512 + n)*16;
    #pragma unroll
    for (int j = 0; j < 16; j += 4){
        *(float4*)(qrow + j) = make_float4(qv[j], qv[j+1], qv[j+2], qv[j+3]);
        *(float4*)(krow + j) = make_float4(kv[j], kv[j+1], kv[j+2], kv[j+3]);
    }
}

// skip accumulation: only last time column matters. skip[b][oc][n] += sb + sw @ xc[:, lastcol]
__global__ void k_skip(const float* __restrict__ xc, int Tout,
                       const float* __restrict__ sw, const float* __restrict__ sb,
                       float* __restrict__ skip){
    int idx = blockIdx.x*256 + threadIdx.x; // 8*256*512
    int n = idx & 511; int oc = (idx >> 9) & 255; int b = idx >> 17;
    const float* base = xc + ((size_t)(b*Tout + (Tout-1))*32)*512 + n;
    float acc = sb[oc];
    #pragma unroll
    for (int c = 0; c < 32; c++) acc += sw[oc*32 + c] * base[c*512];
    skip[idx] += acc;
}

// per-row online softmax stats: rowmax, 1/sum
__global__ __launch_bounds__(256) void k_att_stats(
    const float* __restrict__ qb_, const float* __restrict__ kb_, int T,
    float* __restrict__ rowmax, float* __restrict__ invZ)
{
    __shared__ float ks[512*16];
    int half = blockIdx.x, t = blockIdx.y, b = blockIdx.z;
    int tid = threadIdx.x;
    size_t bt = (size_t)(b*T + t);
    const float* kbase = kb_ + bt*512*16;
    for (int e = tid; e < 8192; e += 256) ks[e] = kbase[e];
    __syncthreads();
    int v = half*256 + tid;
    const float* qrow = qb_ + (bt*512 + v)*16;
    float q[16];
    #pragma unroll
    for (int j = 0; j < 16; j++) q[j] = qrow[j];
    float mx = -1e30f, sm = 0.0f;
    for (int m = 0; m < 512; m++){
        const float* kr = ks + m*16;
        float s = 0.0f;
        #pragma unroll
        for (int j = 0; j < 16; j++) s += q[j]*kr[j];
        s *= 0.25f;
        if (s > mx){ sm = sm * __expf(mx - s); mx = s; }
        sm += __expf(s - mx);
    }
    rowmax[bt*512 + v] = mx;
    invZ[bt*512 + v] = 1.0f / sm;
}

// fused att apply + gmlp + residual -> y (pre-BN), layout [b][Tout][c][n]
__global__ __launch_bounds__(256) void k_att_apply(
    const float* __restrict__ qb_, const float* __restrict__ kb_, const float* __restrict__ xc,
    const float* __restrict__ rowmax, const float* __restrict__ invZ,
    const float* __restrict__ xin, int Tin, int d, int Tout,
    const float* __restrict__ normP,
    const float* __restrict__ gw, const float* __restrict__ gb,
    float* __restrict__ y)
{
    __shared__ float qs[512*16];        // 32 KB
    __shared__ float xcs[512][36];      // ~73.7 KB (padded for banks + 16B align)
    __shared__ float rms[512], izs[512];
    __shared__ float gws[2048];         // 8 KB
    __shared__ float exch[128][33];     // ~16.9 KB
    int tid = threadIdx.x;
    int chunk = blockIdx.x, t = blockIdx.y, b = blockIdx.z;
    size_t bt = (size_t)(b*Tout + t);
    const float* qbase = qb_ + bt*512*16;
    const float* kbase = kb_ + bt*512*16;
    for (int e = tid; e < 8192; e += 256) qs[e] = qbase[e];
    for (int e = tid; e < 16384; e += 256){
        int c = e >> 9; int v = e & 511;
        xcs[v][c] = xc[(bt*32 + c)*512 + v];
    }
    for (int e = tid; e < 512; e += 256){ rms[e] = rowmax[bt*512 + e]; izs[e] = invZ[bt*512 + e]; }
    for (int e = tid; e < 2048; e += 256) gws[e] = gw[e];
    int wl = tid & 127; int halfv = tid >> 7;
    int wg = chunk*128 + wl;
    float kr[16];
    const float* krow = kbase + wg*16;
    #pragma unroll
    for (int j = 0; j < 16; j++) kr[j] = krow[j];
    __syncthreads();
    float acc[32];
    #pragma unroll
    for (int c = 0; c < 32; c++) acc[c] = 0.0f;
    int v0 = halfv*256;
    for (int v = v0; v < v0 + 256; v++){
        const float* qr = qs + v*16;
        float s = 0.0f;
        #pragma unroll
        for (int j = 0; j < 16; j++) s += qr[j]*kr[j];
        float p = __expf(s*0.25f - rms[v]) * izs[v];
        const float* xr = xcs[v];
        #pragma unroll
        for (int c = 0; c < 32; c++) acc[c] += xr[c]*p;
    }
    if (halfv == 1){
        #pragma unroll
        for (int c = 0; c < 32; c++) exch[wl][c] = acc[c];
    }
    __syncthreads();
    if (halfv == 0){
        const float* A = normP; const float* Bc = normP + 32;
        float xa[32];
        #pragma unroll
        for (int c = 0; c < 32; c++) xa[c] = acc[c] + exch[wl][c];
        #pragma unroll
        for (int o = 0; o < 32; o++){
            float a = gb[o];
            const float* g0 = gws + o*64;
            #pragma unroll
            for (int c = 0; c < 32; c++) a += g0[c]*xcs[wg][c] + g0[32 + c]*xa[c];
            float res = A[o]*xin[((size_t)(b*Tin + t + d)*32 + o)*512 + wg] + Bc[o];
            y[(bt*32 + o)*512 + wg] = a + res;
        }
    }
}

// BN batch stats -> scale/shift for next layer's reads
__global__ __launch_bounds__(256) void k_bn(const float* __restrict__ y, int Tout,
                                            const float* __restrict__ g, const float* __restrict__ bb,
                                            float* __restrict__ normPout){
    int c = blockIdx.x; int tid = threadIdx.x;
    int cnt = 8*Tout*512;
    double s = 0.0, s2 = 0.0;
    for (int e = tid; e < cnt; e += 256){
        int n = e & 511; int btq = e >> 9;
        float v = y[((size_t)btq*32 + c)*512 + n];
        s += v; s2 += (double)v*v;
    }
    __shared__ double sh[2][4];
    for (int off = 32; off; off >>= 1){ s += __shfl_down(s, off); s2 += __shfl_down(s2, off); }
    int w = tid >> 6;
    if ((tid & 63) == 0){ sh[0][w] = s; sh[1][w] = s2; }
    __syncthreads();
    if (tid == 0){
        double S = 0.0, S2 = 0.0;
        #pragma unroll
        for (int i = 0; i < 4; i++){ S += sh[0][i]; S2 += sh[1][i]; }
        float m = (float)(S/cnt);
        float var = (float)(S2/cnt) - m*m;
        float Aa = g[c]*rsqrtf(var + 1e-5f);
        normPout[c] = Aa;
        normPout[32 + c] = bb[c] - m*Aa;
    }
}

// final: relu(skip) -> relu(end1) -> end2
__global__ __launch_bounds__(256) void k_end(const float* __restrict__ skip,
                                             const float* __restrict__ w1, const float* __restrict__ b1,
                                             const float* __restrict__ w2, const float* __restrict__ b2,
                                             float* __restrict__ out){
    __shared__ float sk[16][260];
    __shared__ float hs[512][17];
    int tid = threadIdx.x; int ng = blockIdx.x; int b = blockIdx.y;
    int nb = ng*16;
    for (int e = tid; e < 4096; e += 256){
        int oc = e >> 4, nn = e & 15;
        float v = skip[((size_t)b*256 + oc)*512 + nb + nn];
        sk[nn][oc] = fmaxf(v, 0.0f);
    }
    __syncthreads();
    float a0[16], a1[16];
    #pragma unroll
    for (int i = 0; i < 16; i++){ a0[i] = b1[tid]; a1[i] = b1[tid + 256]; }
    for (int c = 0; c < 256; c += 4){
        float4 wA = *(const float4*)(w1 + tid*256 + c);
        float4 wB = *(const float4*)(w1 + (tid + 256)*256 + c);
        #pragma unroll
        for (int nn = 0; nn < 16; nn++){
            float4 s4 = *(const float4*)(&sk[nn][c]);
            a0[nn] += wA.x*s4.x + wA.y*s4.y + wA.z*s4.z + wA.w*s4.w;
            a1[nn] += wB.x*s4.x + wB.y*s4.y + wB.z*s4.z + wB.w*s4.w;
        }
    }
    #pragma unroll
    for (int nn = 0; nn < 16; nn++){
        hs[tid][nn] = fmaxf(a0[nn], 0.0f);
        hs[tid + 256][nn] = fmaxf(a1[nn], 0.0f);
    }
    __syncthreads();
    if (tid < 192){
        int od = tid >> 4, nn = tid & 15;
        float acc = b2[od];
        for (int o = 0; o < 512; o++) acc += w2[od*512 + o]*hs[o][nn];
        out[((size_t)b*12 + od)*512 + nb + nn] = acc;
    }
}

extern "C" void kernel_launch(void* const* d_in, const int* in_sizes, int n_in,
                              void* d_out, int out_size, void* d_ws, size_t ws_size,
                              hipStream_t stream)
{
    (void)in_sizes; (void)n_in; (void)out_size; (void)ws_size;
    const float* input  = (const float*)d_in[0];
    const float* gat    = (const float*)d_in[1];
    const float* start_w= (const float*)d_in[2];
    const float* start_b= (const float*)d_in[3];
    const float* filt_w = (const float*)d_in[4];
    const float* filt_b = (const float*)d_in[5];
    const float* gate_w = (const float*)d_in[6];
    const float* gate_b = (const float*)d_in[7];
    const float* skip_w = (const float*)d_in[8];
    const float* skip_b = (const float*)d_in[9];
    const float* q_w    = (const float*)d_in[10];
    const float* q_b    = (const float*)d_in[11];
    const float* k_w    = (const float*)d_in[12];
    const float* k_b    = (const float*)d_in[13];
    const float* gmlp_w = (const float*)d_in[14];
    const float* gmlp_b = (const float*)d_in[15];
    const float* bn_g   = (const float*)d_in[16];
    const float* bn_b   = (const float*)d_in[17];
    const float* end1_w = (const float*)d_in[18];
    const float* end1_b = (const float*)d_in[19];
    const float* end2_w = (const float*)d_in[20];
    const float* end2_b = (const float*)d_in[21];
    float* out = (float*)d_out;

    float* W = (float*)d_ws;
    size_t off = 0;
    float* bufA = W + off; off += (size_t)8*13*32*512;
    float* bufB = W + off; off += (size_t)8*13*32*512;
    float* xc   = W + off; off += (size_t)8*12*32*512;
    float* qbuf = W + off; off += (size_t)8*12*512*16;
    float* kbuf = W + off; off += (size_t)8*12*512*16;
    float* rowm = W + off; off += (size_t)8*12*512;
    float* izb  = W + off; off += (size_t)8*12*512;
    float* skip = W + off; off += (size_t)8*256*512;
    float* qe   = W + off; off += (size_t)8*512*16;
    float* ke   = W + off; off += (size_t)8*512*16;
    float* normP= W + off; off += (size_t)9*64;

    hipMemsetAsync(skip, 0, (size_t)8*256*512*sizeof(float), stream);
    k_init_norm<<<1, 64, 0, stream>>>(normP);
    k_emb<<<512, 256, 0, stream>>>(q_w, q_b, k_w, k_b, gat, qe, ke);
    k_start<<<6656, 256, 0, stream>>>(input, start_w, start_b, bufA);

    const int Tin[8] = {13,12,10,9,7,6,4,3};
    const int Dd[8]  = {1,2,1,2,1,2,1,2};
    float* xin = bufA; float* yb = bufB;
    for (int i = 0; i < 8; i++){
        int Ti = Tin[i], d = Dd[i], To = Ti - d;
        k_gated<<<dim3(4, To, 8), 128, 0, stream>>>(xin, Ti, d, To, normP + i*64,
            filt_w + i*2048, filt_b + i*32, gate_w + i*2048, gate_b + i*32,
            q_w + i*768, k_w + i*768, qe + i*8192, ke + i*8192, xc, qbuf, kbuf);
        k_skip<<<4096, 256, 0, stream>>>(xc, To, skip_w + i*8192, skip_b + i*256, skip);
        if (i < 7){
            k_att_stats<<<dim3(2, To, 8), 256, 0, stream>>>(qbuf, kbuf, To, rowm, izb);
            k_att_apply<<<dim3(4, To, 8), 256, 0, stream>>>(qbuf, kbuf, xc, rowm, izb,
                xin, Ti, d, To, normP + i*64, gmlp_w + i*2048, gmlp_b + i*32, yb);
            k_bn<<<32, 256, 0, stream>>>(yb, To, bn_g + i*32, bn_b + i*32, normP + (i+1)*64);
            float* tmp = xin; xin = yb; yb = tmp;
        }
    }
    k_end<<<dim3(32, 8), 256, 0, stream>>>(skip, end1_w, end1_b, end2_w, end2_b, out);
}